// Round 4
// baseline (231.944 us; speedup 1.0000x reference)
//
#include <hip/hip_runtime.h>

// Multiprototypes: per-row squared distances to the 3 centers of the row's
// label, min-distance mean (loss1) and entropy-masked min-distance mean (loss2).
//
// B=262144, C=1000, K=3, D=64 (f32). mp_main floor: ~66 MB @ 6.4 TB/s ~= 11.6 us
// (64 MB x + 1 MB labels + <=1 MB centers). Timed region also contains 2x
// 256 MiB harness poison-fills (~83 us) we cannot touch.
//
// v4: single compute kernel. 4 lanes/row (lane owns 16 elems = 4 float4),
// 16 rows/wave, 4 waves/block, NBLK=4096 blocks, 1 row-iter per block (one
// labels->centers gather chain per wave). Cross-block reduction via
// last-block-finalize: release = __threadfence()+atomicAdd (device scope,
// safe across non-coherent XCD L2s), the 4096th block reduces partials in a
// FIXED order (deterministic, no float atomics). Counter re-zeroed per launch
// by a 4-byte hipMemsetAsync (workspace is poisoned between iterations).

#define TH    0.95f
#define EPSF  1e-12f
#define NBLK  4096
#define BLK   256

__device__ __forceinline__ float dist16(const float4 xv0, const float4 xv1,
                                        const float4 xv2, const float4 xv3,
                                        const float4* __restrict__ cb) {
    // cb points at this lane's quarter (sub) of the 64-float center row;
    // quarters are strided 4 float4s apart.
    const float4 c0 = cb[0];
    const float4 c1 = cb[4];
    const float4 c2 = cb[8];
    const float4 c3 = cb[12];
    float d = xv0.x - c0.x; float s = d * d;
    d = xv0.y - c0.y; s = fmaf(d, d, s);
    d = xv0.z - c0.z; s = fmaf(d, d, s);
    d = xv0.w - c0.w; s = fmaf(d, d, s);
    d = xv1.x - c1.x; s = fmaf(d, d, s);
    d = xv1.y - c1.y; s = fmaf(d, d, s);
    d = xv1.z - c1.z; s = fmaf(d, d, s);
    d = xv1.w - c1.w; s = fmaf(d, d, s);
    d = xv2.x - c2.x; s = fmaf(d, d, s);
    d = xv2.y - c2.y; s = fmaf(d, d, s);
    d = xv2.z - c2.z; s = fmaf(d, d, s);
    d = xv2.w - c2.w; s = fmaf(d, d, s);
    d = xv3.x - c3.x; s = fmaf(d, d, s);
    d = xv3.y - c3.y; s = fmaf(d, d, s);
    d = xv3.z - c3.z; s = fmaf(d, d, s);
    d = xv3.w - c3.w; s = fmaf(d, d, s);
    return s;
}

__global__ __launch_bounds__(BLK, 4) void mp_main(
    const float* __restrict__ x,        // [B, 64]
    const int*   __restrict__ labels,   // [B]
    const float* __restrict__ centers,  // [1000, 3, 64]
    float*       __restrict__ partials, // [3 * NBLK] floats, then u32 counter
    unsigned int* __restrict__ counter, // zeroed per launch by memset node
    float*       __restrict__ out,      // [2]
    float invB,
    int B)
{
    const int tid  = threadIdx.x;
    const int lane = tid & 63;
    const int wave = tid >> 6;       // 0..3
    const int sub  = lane & 3;       // quarter of the row (16 floats each)
    const int r    = lane >> 2;      // row-within-wave 0..15

    const float4* __restrict__ x4 = (const float4*)x;
    const float4* __restrict__ c4 = (const float4*)centers;

    const int row = blockIdx.x * 64 + wave * 16 + r;   // B/NBLK = 64 rows/block

    // label first: starts the dependent gather chain as early as possible
    const int lab = labels[row];             // 4 lanes same addr -> broadcast

    // x: per instruction the wave covers 16 rows; 4 loads = 4 KB contiguous
    const float4* xr = x4 + row * 16 + sub;
    const float4 xv0 = xr[0];
    const float4 xv1 = xr[4];
    const float4 xv2 = xr[8];
    const float4 xv3 = xr[12];

    const float4* cb = c4 + lab * 48 + sub;  // lab*(K=3)*(16 float4/row)

    // 12 independent L2 loads in flight; one gather latency per wave total.
    float a0 = dist16(xv0, xv1, xv2, xv3, cb);
    float a1 = dist16(xv0, xv1, xv2, xv3, cb + 16);
    float a2 = dist16(xv0, xv1, xv2, xv3, cb + 32);

    // 4-lane butterfly: every lane of the quad ends with full row sums
    a0 += __shfl_xor(a0, 1); a1 += __shfl_xor(a1, 1); a2 += __shfl_xor(a2, 1);
    a0 += __shfl_xor(a0, 2); a1 += __shfl_xor(a1, 2); a2 += __shfl_xor(a2, 2);

    const float mn  = fminf(a0, fminf(a1, a2));
    const float mx  = fmaxf(a0, fmaxf(a1, a2));
    const float mid = a0 + a1 + a2 - mn - mx;   // second smallest

    const float d0 = mn + EPSF, d1 = mid + EPSF;
    const float p  = d0 / (d0 + d1);            // p <= 0.5, strictly > 0
    const float q  = 1.f - p;
    const float ent = -(p * __log2f(p) + q * __log2f(q));
    const float msk = (ent <= TH) ? 1.f : 0.f;

    float s1 = 0.f, s2 = 0.f, sc = 0.f;
    if (sub == 0) {                             // count each row once
        s1 = mn;
        s2 = msk * mn;
        sc = msk;
    }

    // full-wave (64) butterfly reduce
    #pragma unroll
    for (int m = 1; m <= 32; m <<= 1) {
        s1 += __shfl_xor(s1, m);
        s2 += __shfl_xor(s2, m);
        sc += __shfl_xor(sc, m);
    }

    __shared__ float red[3][4];
    __shared__ unsigned int isLast;
    if (lane == 0) { red[0][wave] = s1; red[1][wave] = s2; red[2][wave] = sc; }
    __syncthreads();
    if (tid == 0) {
        partials[blockIdx.x]              = red[0][0] + red[0][1] + red[0][2] + red[0][3];
        partials[NBLK + blockIdx.x]       = red[1][0] + red[1][1] + red[1][2] + red[1][3];
        partials[2 * NBLK + blockIdx.x]   = red[2][0] + red[2][1] + red[2][2] + red[2][3];
        __threadfence();                               // device-scope release
        const unsigned int old = atomicAdd(counter, 1u);
        isLast = (old == NBLK - 1u) ? 1u : 0u;
    }
    __syncthreads();

    if (isLast) {
        __threadfence();                               // device-scope acquire
        // 256 threads reduce 3*NBLK floats = 3*1024 float4, 4 per thread/array.
        const float4* p4 = (const float4*)partials;
        float t1 = 0.f, t2 = 0.f, t3 = 0.f;
        #pragma unroll
        for (int i = 0; i < 4; ++i) {
            const int idx = i * BLK + tid;             // fixed order -> deterministic
            const float4 v1 = p4[idx];
            const float4 v2 = p4[(NBLK >> 2) + idx];
            const float4 v3 = p4[(NBLK >> 1) + idx];
            t1 += v1.x + v1.y + v1.z + v1.w;
            t2 += v2.x + v2.y + v2.z + v2.w;
            t3 += v3.x + v3.y + v3.z + v3.w;
        }
        #pragma unroll
        for (int m = 1; m <= 32; m <<= 1) {
            t1 += __shfl_xor(t1, m);
            t2 += __shfl_xor(t2, m);
            t3 += __shfl_xor(t3, m);
        }
        __syncthreads();   // red[][] reuse
        if (lane == 0) { red[0][wave] = t1; red[1][wave] = t2; red[2][wave] = t3; }
        __syncthreads();
        if (tid == 0) {
            const float u1 = red[0][0] + red[0][1] + red[0][2] + red[0][3];
            const float u2 = red[1][0] + red[1][1] + red[1][2] + red[1][3];
            const float u3 = red[2][0] + red[2][1] + red[2][2] + red[2][3];
            out[0] = u1 * invB;    // loss1 = mean(min_pos)
            out[1] = u2 / u3;      // loss2 = masked mean
        }
    }
}

extern "C" void kernel_launch(void* const* d_in, const int* in_sizes, int n_in,
                              void* d_out, int out_size, void* d_ws, size_t ws_size,
                              hipStream_t stream) {
    const float* x       = (const float*)d_in[0];
    const int*   labels  = (const int*)d_in[1];
    const float* centers = (const float*)d_in[2];
    float* out      = (float*)d_out;
    float* partials = (float*)d_ws;                      // 3*NBLK floats = 48 KB
    unsigned int* counter = (unsigned int*)((char*)d_ws + 3 * NBLK * sizeof(float));
    const int B = in_sizes[1];        // 262144

    // Workspace is poison-filled between iterations: re-zero the arrival counter.
    hipMemsetAsync(counter, 0, sizeof(unsigned int), stream);
    mp_main<<<NBLK, BLK, 0, stream>>>(x, labels, centers, partials, counter,
                                      out, 1.0f / (float)B, B);
}

// Round 5
// 137.743 us; speedup vs baseline: 1.6839x; 1.6839x over previous
//
#include <hip/hip_runtime.h>

// Multiprototypes: per-row squared distances to the 3 centers of the row's
// label, min-distance mean (loss1) and entropy-masked min-distance mean (loss2).
//
// B=262144, C=1000, K=3, D=64 (f32). mp_main floor: ~66 MB @ 6.4 TB/s ~= 11.6 us
// (less when x is partially L3-resident). Timed region also contains 2x 256 MiB
// harness poison-fills (~83 us) we cannot touch.
//
// v5: single compute kernel, last-block finalize WITHOUT device fences.
// v4's __threadfence() emitted buffer_wbl2 (full L2 writeback) per block ->
// 4096-block fence storm, 200 us. Fix: per-block partials are stored with
// agent-scope relaxed atomic stores (sc1 -> write-through the non-coherent
// XCD L2 to the coherent memory-side Infinity Cache), ordered before the
// arrival atomic by a raw s_waitcnt vmcnt(0). The single last block does one
// acquire fence (buffer_inv: invalidate-only, no writeback) and then reads
// partials with plain vectorized loads. Fixed-order reduce -> deterministic.

#define TH    0.95f
#define EPSF  1e-12f
#define NBLK  4096
#define BLK   256

__device__ __forceinline__ float dist16(const float4 xv0, const float4 xv1,
                                        const float4 xv2, const float4 xv3,
                                        const float4* __restrict__ cb) {
    // cb points at this lane's quarter (sub) of the 64-float center row;
    // quarters are strided 4 float4s apart.
    const float4 c0 = cb[0];
    const float4 c1 = cb[4];
    const float4 c2 = cb[8];
    const float4 c3 = cb[12];
    float d = xv0.x - c0.x; float s = d * d;
    d = xv0.y - c0.y; s = fmaf(d, d, s);
    d = xv0.z - c0.z; s = fmaf(d, d, s);
    d = xv0.w - c0.w; s = fmaf(d, d, s);
    d = xv1.x - c1.x; s = fmaf(d, d, s);
    d = xv1.y - c1.y; s = fmaf(d, d, s);
    d = xv1.z - c1.z; s = fmaf(d, d, s);
    d = xv1.w - c1.w; s = fmaf(d, d, s);
    d = xv2.x - c2.x; s = fmaf(d, d, s);
    d = xv2.y - c2.y; s = fmaf(d, d, s);
    d = xv2.z - c2.z; s = fmaf(d, d, s);
    d = xv2.w - c2.w; s = fmaf(d, d, s);
    d = xv3.x - c3.x; s = fmaf(d, d, s);
    d = xv3.y - c3.y; s = fmaf(d, d, s);
    d = xv3.z - c3.z; s = fmaf(d, d, s);
    d = xv3.w - c3.w; s = fmaf(d, d, s);
    return s;
}

__global__ __launch_bounds__(BLK, 4) void mp_main(
    const float* __restrict__ x,        // [B, 64]
    const int*   __restrict__ labels,   // [B]
    const float* __restrict__ centers,  // [1000, 3, 64]
    float*       __restrict__ partials, // [3 * NBLK] floats
    unsigned int* __restrict__ counter, // zeroed per launch by memset node
    float*       __restrict__ out,      // [2]
    float invB,
    int B)
{
    const int tid  = threadIdx.x;
    const int lane = tid & 63;
    const int wave = tid >> 6;       // 0..3
    const int sub  = lane & 3;       // quarter of the row (16 floats each)
    const int r    = lane >> 2;      // row-within-wave 0..15

    const float4* __restrict__ x4 = (const float4*)x;
    const float4* __restrict__ c4 = (const float4*)centers;

    const int row = blockIdx.x * 64 + wave * 16 + r;   // B/NBLK = 64 rows/block

    // label first: starts the dependent gather chain as early as possible
    const int lab = labels[row];             // 4 lanes same addr -> broadcast

    // x: per instruction the wave covers 16 rows; 4 loads = 4 KB contiguous
    const float4* xr = x4 + row * 16 + sub;
    const float4 xv0 = xr[0];
    const float4 xv1 = xr[4];
    const float4 xv2 = xr[8];
    const float4 xv3 = xr[12];

    const float4* cb = c4 + lab * 48 + sub;  // lab*(K=3)*(16 float4/row)

    // 12 independent L2 loads in flight; one gather latency per wave total.
    float a0 = dist16(xv0, xv1, xv2, xv3, cb);
    float a1 = dist16(xv0, xv1, xv2, xv3, cb + 16);
    float a2 = dist16(xv0, xv1, xv2, xv3, cb + 32);

    // 4-lane butterfly: every lane of the quad ends with full row sums
    a0 += __shfl_xor(a0, 1); a1 += __shfl_xor(a1, 1); a2 += __shfl_xor(a2, 1);
    a0 += __shfl_xor(a0, 2); a1 += __shfl_xor(a1, 2); a2 += __shfl_xor(a2, 2);

    const float mn  = fminf(a0, fminf(a1, a2));
    const float mx  = fmaxf(a0, fmaxf(a1, a2));
    const float mid = a0 + a1 + a2 - mn - mx;   // second smallest

    const float d0 = mn + EPSF, d1 = mid + EPSF;
    const float p  = d0 / (d0 + d1);            // p <= 0.5, strictly > 0
    const float q  = 1.f - p;
    const float ent = -(p * __log2f(p) + q * __log2f(q));
    const float msk = (ent <= TH) ? 1.f : 0.f;

    float s1 = 0.f, s2 = 0.f, sc = 0.f;
    if (sub == 0) {                             // count each row once
        s1 = mn;
        s2 = msk * mn;
        sc = msk;
    }

    // full-wave (64) butterfly reduce
    #pragma unroll
    for (int m = 1; m <= 32; m <<= 1) {
        s1 += __shfl_xor(s1, m);
        s2 += __shfl_xor(s2, m);
        sc += __shfl_xor(sc, m);
    }

    __shared__ float red[3][4];
    __shared__ unsigned int isLast;
    if (lane == 0) { red[0][wave] = s1; red[1][wave] = s2; red[2][wave] = sc; }
    __syncthreads();
    if (tid == 0) {
        const float p1 = red[0][0] + red[0][1] + red[0][2] + red[0][3];
        const float p2 = red[1][0] + red[1][1] + red[1][2] + red[1][3];
        const float p3 = red[2][0] + red[2][1] + red[2][2] + red[2][3];
        // sc1 write-through stores: visible at the coherent memory-side cache
        // without any L2 writeback fence.
        __hip_atomic_store(&partials[blockIdx.x],            p1,
                           __ATOMIC_RELAXED, __HIP_MEMORY_SCOPE_AGENT);
        __hip_atomic_store(&partials[NBLK + blockIdx.x],     p2,
                           __ATOMIC_RELAXED, __HIP_MEMORY_SCOPE_AGENT);
        __hip_atomic_store(&partials[2 * NBLK + blockIdx.x], p3,
                           __ATOMIC_RELAXED, __HIP_MEMORY_SCOPE_AGENT);
        // store-acks received => globally visible; then announce arrival.
        asm volatile("s_waitcnt vmcnt(0)" ::: "memory");
        const unsigned int old = __hip_atomic_fetch_add(
            counter, 1u, __ATOMIC_RELAXED, __HIP_MEMORY_SCOPE_AGENT);
        isLast = (old == NBLK - 1u) ? 1u : 0u;
    }
    __syncthreads();

    if (isLast) {
        // acquire: buffer_inv (invalidate-only, once, no writeback traffic) so
        // plain vectorized loads below read through to the coherent point.
        __builtin_amdgcn_fence(__ATOMIC_ACQUIRE, "agent");
        // 256 threads reduce 3*NBLK floats = 3*1024 float4, 4 per thread/array.
        const float4* p4 = (const float4*)partials;
        float t1 = 0.f, t2 = 0.f, t3 = 0.f;
        #pragma unroll
        for (int i = 0; i < 4; ++i) {
            const int idx = i * BLK + tid;             // fixed order -> deterministic
            const float4 v1 = p4[idx];
            const float4 v2 = p4[(NBLK >> 2) + idx];
            const float4 v3 = p4[(NBLK >> 1) + idx];
            t1 += v1.x + v1.y + v1.z + v1.w;
            t2 += v2.x + v2.y + v2.z + v2.w;
            t3 += v3.x + v3.y + v3.z + v3.w;
        }
        #pragma unroll
        for (int m = 1; m <= 32; m <<= 1) {
            t1 += __shfl_xor(t1, m);
            t2 += __shfl_xor(t2, m);
            t3 += __shfl_xor(t3, m);
        }
        __syncthreads();   // red[][] reuse
        if (lane == 0) { red[0][wave] = t1; red[1][wave] = t2; red[2][wave] = t3; }
        __syncthreads();
        if (tid == 0) {
            const float u1 = red[0][0] + red[0][1] + red[0][2] + red[0][3];
            const float u2 = red[1][0] + red[1][1] + red[1][2] + red[1][3];
            const float u3 = red[2][0] + red[2][1] + red[2][2] + red[2][3];
            out[0] = u1 * invB;    // loss1 = mean(min_pos)
            out[1] = u2 / u3;      // loss2 = masked mean
        }
    }
}

extern "C" void kernel_launch(void* const* d_in, const int* in_sizes, int n_in,
                              void* d_out, int out_size, void* d_ws, size_t ws_size,
                              hipStream_t stream) {
    const float* x       = (const float*)d_in[0];
    const int*   labels  = (const int*)d_in[1];
    const float* centers = (const float*)d_in[2];
    float* out      = (float*)d_out;
    float* partials = (float*)d_ws;                      // 3*NBLK floats = 48 KB
    unsigned int* counter = (unsigned int*)((char*)d_ws + 3 * NBLK * sizeof(float));
    const int B = in_sizes[1];        // 262144

    // Workspace is poison-filled between iterations: re-zero the arrival counter.
    hipMemsetAsync(counter, 0, sizeof(unsigned int), stream);
    mp_main<<<NBLK, BLK, 0, stream>>>(x, labels, centers, partials, counter,
                                      out, 1.0f / (float)B, B);
}

// Round 6
// 102.295 us; speedup vs baseline: 2.2674x; 1.3465x over previous
//
#include <hip/hip_runtime.h>

// Multiprototypes: per-row squared distances to the 3 centers of the row's
// label, min-distance mean (loss1) and entropy-masked min-distance mean (loss2).
//
// B=262144, C=1000, K=3, D=64 (f32). mp_main data floor ~12 us (66 MB inputs,
// partially L3-resident -> FETCH ~36 MB). Timed region also contains 2x 256 MiB
// harness poison-fills (~83 us) we cannot touch.
//
// v6: single fused kernel; last-block finalize with a TWO-LEVEL arrival tree.
//  - v4 lesson: __threadfence() per block = buffer_wbl2 storm (200 us).
//  - v5 lesson: 4096 same-address agent atomics serialize at the coherent
//    point (~12 ns each -> 49 us; measured 57 us total, HBM 8%).
//  - v6: partials stored with agent-scope sc1 stores (write-through, no L2
//    writeback), ordered by s_waitcnt vmcnt(0); arrival = atomicAdd on one of
//    64 group counters (64 adds each, own 128 B line), group leader then adds
//    to ONE final counter (64 adds). Global last block does one invalidate-only
//    acquire fence and reduces all partials in a FIXED order (deterministic,
//    no float atomics).

#define TH    0.95f
#define EPSF  1e-12f
#define NBLK  4096
#define BLK   256
#define NGRP  64
#define GRPSZ (NBLK / NGRP)        // 64
#define CNT_STRIDE 32              // uints -> 128 B per group counter

__device__ __forceinline__ float dist16(const float4 xv0, const float4 xv1,
                                        const float4 xv2, const float4 xv3,
                                        const float4* __restrict__ cb) {
    // cb points at this lane's quarter (sub) of the 64-float center row;
    // quarters are strided 4 float4s apart.
    const float4 c0 = cb[0];
    const float4 c1 = cb[4];
    const float4 c2 = cb[8];
    const float4 c3 = cb[12];
    float d = xv0.x - c0.x; float s = d * d;
    d = xv0.y - c0.y; s = fmaf(d, d, s);
    d = xv0.z - c0.z; s = fmaf(d, d, s);
    d = xv0.w - c0.w; s = fmaf(d, d, s);
    d = xv1.x - c1.x; s = fmaf(d, d, s);
    d = xv1.y - c1.y; s = fmaf(d, d, s);
    d = xv1.z - c1.z; s = fmaf(d, d, s);
    d = xv1.w - c1.w; s = fmaf(d, d, s);
    d = xv2.x - c2.x; s = fmaf(d, d, s);
    d = xv2.y - c2.y; s = fmaf(d, d, s);
    d = xv2.z - c2.z; s = fmaf(d, d, s);
    d = xv2.w - c2.w; s = fmaf(d, d, s);
    d = xv3.x - c3.x; s = fmaf(d, d, s);
    d = xv3.y - c3.y; s = fmaf(d, d, s);
    d = xv3.z - c3.z; s = fmaf(d, d, s);
    d = xv3.w - c3.w; s = fmaf(d, d, s);
    return s;
}

__global__ __launch_bounds__(BLK, 4) void mp_main(
    const float* __restrict__ x,        // [B, 64]
    const int*   __restrict__ labels,   // [B]
    const float* __restrict__ centers,  // [1000, 3, 64]
    float*        __restrict__ partials,// [3 * NBLK] floats
    unsigned int* __restrict__ gcnt,    // [NGRP * CNT_STRIDE], zeroed per launch
    unsigned int* __restrict__ fcnt,    // [1], zeroed per launch
    float*        __restrict__ out,     // [2]
    float invB,
    int B)
{
    const int tid  = threadIdx.x;
    const int lane = tid & 63;
    const int wave = tid >> 6;       // 0..3
    const int sub  = lane & 3;       // quarter of the row (16 floats each)
    const int r    = lane >> 2;      // row-within-wave 0..15

    const float4* __restrict__ x4 = (const float4*)x;
    const float4* __restrict__ c4 = (const float4*)centers;

    const int row = blockIdx.x * 64 + wave * 16 + r;   // B/NBLK = 64 rows/block

    // label first: starts the dependent gather chain as early as possible
    const int lab = labels[row];             // 4 lanes same addr -> broadcast

    // x: per instruction the wave covers 16 rows; 4 loads = 4 KB contiguous
    const float4* xr = x4 + row * 16 + sub;
    const float4 xv0 = xr[0];
    const float4 xv1 = xr[4];
    const float4 xv2 = xr[8];
    const float4 xv3 = xr[12];

    const float4* cb = c4 + lab * 48 + sub;  // lab*(K=3)*(16 float4/row)

    // 12 independent L2 loads in flight; one gather latency per wave total.
    float a0 = dist16(xv0, xv1, xv2, xv3, cb);
    float a1 = dist16(xv0, xv1, xv2, xv3, cb + 16);
    float a2 = dist16(xv0, xv1, xv2, xv3, cb + 32);

    // 4-lane butterfly: every lane of the quad ends with full row sums
    a0 += __shfl_xor(a0, 1); a1 += __shfl_xor(a1, 1); a2 += __shfl_xor(a2, 1);
    a0 += __shfl_xor(a0, 2); a1 += __shfl_xor(a1, 2); a2 += __shfl_xor(a2, 2);

    const float mn  = fminf(a0, fminf(a1, a2));
    const float mx  = fmaxf(a0, fmaxf(a1, a2));
    const float mid = a0 + a1 + a2 - mn - mx;   // second smallest

    const float d0 = mn + EPSF, d1 = mid + EPSF;
    const float p  = d0 / (d0 + d1);            // p <= 0.5, strictly > 0
    const float q  = 1.f - p;
    const float ent = -(p * __log2f(p) + q * __log2f(q));
    const float msk = (ent <= TH) ? 1.f : 0.f;

    float s1 = 0.f, s2 = 0.f, sc = 0.f;
    if (sub == 0) {                             // count each row once
        s1 = mn;
        s2 = msk * mn;
        sc = msk;
    }

    // full-wave (64) butterfly reduce
    #pragma unroll
    for (int m = 1; m <= 32; m <<= 1) {
        s1 += __shfl_xor(s1, m);
        s2 += __shfl_xor(s2, m);
        sc += __shfl_xor(sc, m);
    }

    __shared__ float red[3][4];
    __shared__ unsigned int isLast;
    if (lane == 0) { red[0][wave] = s1; red[1][wave] = s2; red[2][wave] = sc; }
    __syncthreads();
    if (tid == 0) {
        const float p1 = red[0][0] + red[0][1] + red[0][2] + red[0][3];
        const float p2 = red[1][0] + red[1][1] + red[1][2] + red[1][3];
        const float p3 = red[2][0] + red[2][1] + red[2][2] + red[2][3];
        // sc1 write-through stores: visible at the coherent memory-side cache
        // without any L2 writeback fence.
        __hip_atomic_store(&partials[blockIdx.x],            p1,
                           __ATOMIC_RELAXED, __HIP_MEMORY_SCOPE_AGENT);
        __hip_atomic_store(&partials[NBLK + blockIdx.x],     p2,
                           __ATOMIC_RELAXED, __HIP_MEMORY_SCOPE_AGENT);
        __hip_atomic_store(&partials[2 * NBLK + blockIdx.x], p3,
                           __ATOMIC_RELAXED, __HIP_MEMORY_SCOPE_AGENT);
        // store-acks received => globally visible; then announce arrival.
        asm volatile("s_waitcnt vmcnt(0)" ::: "memory");
        const int grp = blockIdx.x >> 6;             // 64 consecutive blocks/group
        unsigned int last = 0u;
        const unsigned int og = __hip_atomic_fetch_add(
            &gcnt[grp * CNT_STRIDE], 1u, __ATOMIC_RELAXED, __HIP_MEMORY_SCOPE_AGENT);
        if (og == GRPSZ - 1u) {
            // group complete (incl. all members' vmcnt-ordered partials);
            // control-dependence on og orders this after the group add.
            const unsigned int of = __hip_atomic_fetch_add(
                fcnt, 1u, __ATOMIC_RELAXED, __HIP_MEMORY_SCOPE_AGENT);
            last = (of == NGRP - 1u) ? 1u : 0u;
        }
        isLast = last;
    }
    __syncthreads();

    if (isLast) {
        // acquire: buffer_inv (invalidate-only, once, no writeback traffic) so
        // plain vectorized loads below read through to the coherent point.
        __builtin_amdgcn_fence(__ATOMIC_ACQUIRE, "agent");
        // 256 threads reduce 3*NBLK floats = 3*1024 float4, 4 per thread/array.
        const float4* p4 = (const float4*)partials;
        float t1 = 0.f, t2 = 0.f, t3 = 0.f;
        #pragma unroll
        for (int i = 0; i < 4; ++i) {
            const int idx = i * BLK + tid;             // fixed order -> deterministic
            const float4 v1 = p4[idx];
            const float4 v2 = p4[(NBLK >> 2) + idx];
            const float4 v3 = p4[(NBLK >> 1) + idx];
            t1 += v1.x + v1.y + v1.z + v1.w;
            t2 += v2.x + v2.y + v2.z + v2.w;
            t3 += v3.x + v3.y + v3.z + v3.w;
        }
        #pragma unroll
        for (int m = 1; m <= 32; m <<= 1) {
            t1 += __shfl_xor(t1, m);
            t2 += __shfl_xor(t2, m);
            t3 += __shfl_xor(t3, m);
        }
        __syncthreads();   // red[][] reuse
        if (lane == 0) { red[0][wave] = t1; red[1][wave] = t2; red[2][wave] = t3; }
        __syncthreads();
        if (tid == 0) {
            const float u1 = red[0][0] + red[0][1] + red[0][2] + red[0][3];
            const float u2 = red[1][0] + red[1][1] + red[1][2] + red[1][3];
            const float u3 = red[2][0] + red[2][1] + red[2][2] + red[2][3];
            out[0] = u1 * invB;    // loss1 = mean(min_pos)
            out[1] = u2 / u3;      // loss2 = masked mean
        }
    }
}

extern "C" void kernel_launch(void* const* d_in, const int* in_sizes, int n_in,
                              void* d_out, int out_size, void* d_ws, size_t ws_size,
                              hipStream_t stream) {
    const float* x       = (const float*)d_in[0];
    const int*   labels  = (const int*)d_in[1];
    const float* centers = (const float*)d_in[2];
    float* out      = (float*)d_out;
    float* partials = (float*)d_ws;                       // 3*NBLK floats = 48 KB
    unsigned int* gcnt = (unsigned int*)((char*)d_ws + 3 * NBLK * sizeof(float));
    unsigned int* fcnt = gcnt + NGRP * CNT_STRIDE;        // right after group counters
    const int B = in_sizes[1];        // 262144

    // Workspace is poison-filled between iterations: re-zero all counters
    // (NGRP group counters @128 B stride + final counter) in one small memset.
    hipMemsetAsync(gcnt, 0, (NGRP * CNT_STRIDE + CNT_STRIDE) * sizeof(unsigned int),
                   stream);
    mp_main<<<NBLK, BLK, 0, stream>>>(x, labels, centers, partials, gcnt, fcnt,
                                      out, 1.0f / (float)B, B);
}

// Round 7
// 101.510 us; speedup vs baseline: 2.2849x; 1.0077x over previous
//
#include <hip/hip_runtime.h>

// Multiprototypes: per-row squared distances to the 3 centers of the row's
// label, min-distance mean (loss1) and entropy-masked min-distance mean (loss2).
//
// B=262144, C=1000, K=3, D=64 (f32). mp_main floor: ~66 MB @ 6.4 TB/s ~= 11.6 us
// (64 MB x + 1 MB labels; centers L2-resident). Timed region also contains 2x
// 256 MiB harness poison-fills (~83 us) that are themselves HBM-roofline-bound.
//
// v7 == v3 (best measured, 100.8 us): two-kernel deterministic reduction.
// Fusion attempts (v4 fence: 232 us L2-writeback storm; v5 flat atomic: 138 us
// same-address serialization; v6 two-level tree: 102.3 us) all cost >= the
// ~2-4 us launch gap they try to save. Keep the simple structure.
//
// Mapping: 4 lanes per row (each lane owns 16 elements = 4 float4),
// 16 rows/wave, 4 waves/block -> 64 rows per block, NBLK=4096 blocks, ONE
// row-iteration per block: exactly one labels->centers dependent-gather chain
// per wave, hidden by ~16 resident waves/CU. No float atomics -> bitwise
// deterministic (absmax 0.0).

#define TH   0.95f
#define EPSF 1e-12f
#define NBLK 4096
#define BLK  256
#define BLKF 1024

__device__ __forceinline__ float dist16(const float4 xv0, const float4 xv1,
                                        const float4 xv2, const float4 xv3,
                                        const float4* __restrict__ cb) {
    // cb points at this lane's quarter (sub) of the 64-float center row;
    // quarters are strided 4 float4s apart.
    const float4 c0 = cb[0];
    const float4 c1 = cb[4];
    const float4 c2 = cb[8];
    const float4 c3 = cb[12];
    float d = xv0.x - c0.x; float s = d * d;
    d = xv0.y - c0.y; s = fmaf(d, d, s);
    d = xv0.z - c0.z; s = fmaf(d, d, s);
    d = xv0.w - c0.w; s = fmaf(d, d, s);
    d = xv1.x - c1.x; s = fmaf(d, d, s);
    d = xv1.y - c1.y; s = fmaf(d, d, s);
    d = xv1.z - c1.z; s = fmaf(d, d, s);
    d = xv1.w - c1.w; s = fmaf(d, d, s);
    d = xv2.x - c2.x; s = fmaf(d, d, s);
    d = xv2.y - c2.y; s = fmaf(d, d, s);
    d = xv2.z - c2.z; s = fmaf(d, d, s);
    d = xv2.w - c2.w; s = fmaf(d, d, s);
    d = xv3.x - c3.x; s = fmaf(d, d, s);
    d = xv3.y - c3.y; s = fmaf(d, d, s);
    d = xv3.z - c3.z; s = fmaf(d, d, s);
    d = xv3.w - c3.w; s = fmaf(d, d, s);
    return s;
}

__global__ __launch_bounds__(BLK, 4) void mp_main(
    const float* __restrict__ x,        // [B, 64]
    const int*   __restrict__ labels,   // [B]
    const float* __restrict__ centers,  // [1000, 3, 64]
    float*       __restrict__ partials, // [3 * NBLK]
    int B)
{
    const int tid  = threadIdx.x;
    const int lane = tid & 63;
    const int wave = tid >> 6;       // 0..3
    const int sub  = lane & 3;       // quarter of the row (16 floats each)
    const int r    = lane >> 2;      // row-within-wave 0..15

    const float4* __restrict__ x4 = (const float4*)x;
    const float4* __restrict__ c4 = (const float4*)centers;

    const int row = blockIdx.x * 64 + wave * 16 + r;   // B/NBLK = 64 rows/block

    // label first: starts the dependent gather chain as early as possible
    const int lab = labels[row];             // 4 lanes same addr -> broadcast

    // x: per instruction the wave covers 16 rows; 4 loads = 4 KB contiguous
    const float4* xr = x4 + row * 16 + sub;
    const float4 xv0 = xr[0];
    const float4 xv1 = xr[4];
    const float4 xv2 = xr[8];
    const float4 xv3 = xr[12];

    const float4* cb = c4 + lab * 48 + sub;  // lab*(K=3)*(16 float4/row)

    // 12 independent L2 loads in flight; one gather latency per wave total.
    float a0 = dist16(xv0, xv1, xv2, xv3, cb);
    float a1 = dist16(xv0, xv1, xv2, xv3, cb + 16);
    float a2 = dist16(xv0, xv1, xv2, xv3, cb + 32);

    // 4-lane butterfly: every lane of the quad ends with full row sums
    a0 += __shfl_xor(a0, 1); a1 += __shfl_xor(a1, 1); a2 += __shfl_xor(a2, 1);
    a0 += __shfl_xor(a0, 2); a1 += __shfl_xor(a1, 2); a2 += __shfl_xor(a2, 2);

    const float mn  = fminf(a0, fminf(a1, a2));
    const float mx  = fmaxf(a0, fmaxf(a1, a2));
    const float mid = a0 + a1 + a2 - mn - mx;   // second smallest

    const float d0 = mn + EPSF, d1 = mid + EPSF;
    const float p  = d0 / (d0 + d1);            // p <= 0.5, strictly > 0
    const float q  = 1.f - p;
    const float ent = -(p * __log2f(p) + q * __log2f(q));
    const float msk = (ent <= TH) ? 1.f : 0.f;

    float s1 = 0.f, s2 = 0.f, sc = 0.f;
    if (sub == 0) {                             // count each row once
        s1 = mn;
        s2 = msk * mn;
        sc = msk;
    }

    // full-wave (64) butterfly reduce
    #pragma unroll
    for (int m = 1; m <= 32; m <<= 1) {
        s1 += __shfl_xor(s1, m);
        s2 += __shfl_xor(s2, m);
        sc += __shfl_xor(sc, m);
    }

    __shared__ float red[3][4];
    if (lane == 0) { red[0][wave] = s1; red[1][wave] = s2; red[2][wave] = sc; }
    __syncthreads();
    if (tid == 0) {
        partials[blockIdx.x]              = red[0][0] + red[0][1] + red[0][2] + red[0][3];
        partials[NBLK + blockIdx.x]       = red[1][0] + red[1][1] + red[1][2] + red[1][3];
        partials[2 * NBLK + blockIdx.x]   = red[2][0] + red[2][1] + red[2][2] + red[2][3];
    }
}

__global__ __launch_bounds__(BLKF) void mp_final(
    const float* __restrict__ partials, float* __restrict__ out, float invB)
{
    const int tid  = threadIdx.x;
    const int lane = tid & 63;
    const int wave = tid >> 6;       // 0..15

    // 3*NBLK floats = 3*1024 float4; exactly one float4 per thread per array.
    const float4* p4 = (const float4*)partials;
    const float4 v1 = p4[tid];                    // partials[0      .. NBLK)
    const float4 v2 = p4[(NBLK >> 2) + tid];      // partials[NBLK   .. 2NBLK)
    const float4 v3 = p4[(NBLK >> 1) + tid];      // partials[2NBLK  .. 3NBLK)

    float s1 = v1.x + v1.y + v1.z + v1.w;
    float s2 = v2.x + v2.y + v2.z + v2.w;
    float sc = v3.x + v3.y + v3.z + v3.w;

    #pragma unroll
    for (int m = 1; m <= 32; m <<= 1) {
        s1 += __shfl_xor(s1, m);
        s2 += __shfl_xor(s2, m);
        sc += __shfl_xor(sc, m);
    }

    __shared__ float red[3][16];
    if (lane == 0) { red[0][wave] = s1; red[1][wave] = s2; red[2][wave] = sc; }
    __syncthreads();
    if (tid == 0) {
        float t1 = 0.f, t2 = 0.f, t3 = 0.f;
        #pragma unroll
        for (int i = 0; i < 16; ++i) { t1 += red[0][i]; t2 += red[1][i]; t3 += red[2][i]; }
        out[0] = t1 * invB;    // loss1 = mean(min_pos)
        out[1] = t2 / t3;      // loss2 = masked mean
    }
}

extern "C" void kernel_launch(void* const* d_in, const int* in_sizes, int n_in,
                              void* d_out, int out_size, void* d_ws, size_t ws_size,
                              hipStream_t stream) {
    const float* x       = (const float*)d_in[0];
    const int*   labels  = (const int*)d_in[1];
    const float* centers = (const float*)d_in[2];
    float* out      = (float*)d_out;
    float* partials = (float*)d_ws;   // 3*NBLK floats = 48 KB
    const int B = in_sizes[1];        // 262144

    mp_main<<<NBLK, BLK, 0, stream>>>(x, labels, centers, partials, B);
    mp_final<<<1, BLKF, 0, stream>>>(partials, out, 1.0f / (float)B);
}